// Round 1
// baseline (259.003 us; speedup 1.0000x reference)
//
#include <hip/hip_runtime.h>
#include <hip/hip_bf16.h>
#include <stdint.h>
#include <stddef.h>

#define BATCH 4096
#define INF   1024
#define OUTF  1024
#define NG    8
#define KDIM  (INF * NG)      // 8192
#define BK    64
#define NT    (KDIM / BK)     // 128

typedef __attribute__((ext_vector_type(8))) short  short8;
typedef __attribute__((ext_vector_type(4))) float  f32x4;

// grid knots, computed exactly as the reference: arange(-3..8) * 0.4f + (-1.0f), fp32
__device__ constexpr float knot(int j) { return (float)(j - 3) * 0.4f - 1.0f; }

// ---------------------------------------------------------------------------
// Kernel 1: B-spline bases. One thread per (b,i); writes 8 bf16 (16 B) coalesced.
// A[b][i*8+g] = bases_g(x[b,i])
// ---------------------------------------------------------------------------
__global__ __launch_bounds__(256) void kan_bases(const float* __restrict__ x,
                                                 short8* __restrict__ A) {
    size_t idx = (size_t)blockIdx.x * 256 + threadIdx.x;   // 0 .. 4096*1024-1
    float xv = x[idx];

    float b[11];
#pragma unroll
    for (int j = 0; j < 11; ++j)
        b[j] = (xv >= knot(j) && xv < knot(j + 1)) ? 1.0f : 0.0f;

#pragma unroll
    for (int k = 1; k <= 3; ++k) {
#pragma unroll
        for (int j = 0; j + k < 11; ++j) {
            float left  = (xv - knot(j))         / (knot(j + k)     - knot(j));
            float right = (knot(j + k + 1) - xv) / (knot(j + k + 1) - knot(j + 1));
            b[j] = left * b[j] + right * b[j + 1];
        }
    }

    union { short8 v; unsigned short u[8]; } pk;
#pragma unroll
    for (int g = 0; g < 8; ++g) {
        __hip_bfloat16 h = __float2bfloat16(b[g]);
        pk.u[g] = *reinterpret_cast<unsigned short*>(&h);
    }
    A[idx] = pk.v;
}

// ---------------------------------------------------------------------------
// Kernel 2: weight fp32 -> bf16. 8 elements per thread.
// spline_weight (O,I,G) flat == B^T[o][k=i*8+g], layout already GEMM-ready.
// ---------------------------------------------------------------------------
__global__ __launch_bounds__(256) void kan_wconv(const f32x4* __restrict__ w,
                                                 short8* __restrict__ Wb) {
    size_t idx = (size_t)blockIdx.x * 256 + threadIdx.x;   // per 8 elements
    f32x4 a = w[idx * 2];
    f32x4 c = w[idx * 2 + 1];
    float t[8] = {a[0], a[1], a[2], a[3], c[0], c[1], c[2], c[3]};
    union { short8 v; unsigned short u[8]; } pk;
#pragma unroll
    for (int g = 0; g < 8; ++g) {
        __hip_bfloat16 h = __float2bfloat16(t[g]);
        pk.u[g] = *reinterpret_cast<unsigned short*>(&h);
    }
    Wb[idx] = pk.v;
}

// ---------------------------------------------------------------------------
// Kernel 3: bf16 GEMM  C[4096,1024] = A[4096,8192] * B^T[1024,8192]^T
// 128x128 tile, BK=64, 256 threads (4 waves, 64x64 each, 4x4 frags of 16x16x32).
// Double-buffered LDS + global_load_lds(16B) + counted vmcnt(8) + raw barriers.
// ---------------------------------------------------------------------------
__device__ __forceinline__ void gload16(const void* g, void* l) {
    __builtin_amdgcn_global_load_lds((const __attribute__((address_space(1))) void*)g,
                                     (__attribute__((address_space(3))) void*)l,
                                     16, 0, 0);
}

__global__ __launch_bounds__(256, 1) void kan_gemm(const __hip_bfloat16* __restrict__ A,
                                                   const __hip_bfloat16* __restrict__ Bt,
                                                   float* __restrict__ C) {
    __shared__ __hip_bfloat16 sA[2][128 * 64];
    __shared__ __hip_bfloat16 sB[2][128 * 64];

    const int tid = threadIdx.x;
    const int bm = blockIdx.x >> 3;       // 0..31
    const int bn = blockIdx.x & 7;        // 0..7
    const int m0 = bm << 7;
    const int n0 = bn << 7;

    // staging: thread t loads 8 bf16 (16 B); rows srow + r*32, cols scol..scol+7
    const int srow = tid >> 3;            // 0..31
    const int scol = (tid & 7) << 3;      // 0..56
    const __hip_bfloat16* gA = A  + (size_t)(m0 + srow) * KDIM + scol;
    const __hip_bfloat16* gB = Bt + (size_t)(n0 + srow) * KDIM + scol;
    const int soff = srow * 64 + scol;    // LDS element offset (wave-uniform+lane*8 elems)

    // compute: wave w -> 64x64 quadrant (wr, wc)
    const int w    = tid >> 6;
    const int lane = tid & 63;
    const int wr   = (w >> 1) << 6;       // 0 or 64
    const int wc   = (w & 1) << 6;        // 0 or 64
    const int lr   = lane & 15;
    const int lk   = lane >> 4;           // 0..3

    f32x4 acc[4][4];
#pragma unroll
    for (int i = 0; i < 4; ++i)
#pragma unroll
        for (int j = 0; j < 4; ++j)
            acc[i][j] = (f32x4){0.0f, 0.0f, 0.0f, 0.0f};

#define STAGE(buf, kt) do {                                                   \
        const __hip_bfloat16* _ga = gA + (size_t)(kt) * BK;                   \
        const __hip_bfloat16* _gb = gB + (size_t)(kt) * BK;                   \
        _Pragma("unroll")                                                     \
        for (int r = 0; r < 4; ++r) {                                         \
            gload16(_ga + (size_t)(r * 32) * KDIM, &sA[buf][r * 2048 + soff]);\
            gload16(_gb + (size_t)(r * 32) * KDIM, &sB[buf][r * 2048 + soff]);\
        }                                                                     \
    } while (0)

    STAGE(0, 0);

    for (int kt = 0; kt < NT; ++kt) {
        const int cur = kt & 1;
        if (kt + 1 < NT) {
            STAGE(cur ^ 1, kt + 1);                       // prefetch next tile
            asm volatile("s_waitcnt vmcnt(8)" ::: "memory");  // tile kt landed; next 8 in flight
        } else {
            asm volatile("s_waitcnt vmcnt(0)" ::: "memory");
        }
        __builtin_amdgcn_s_barrier();

        const __hip_bfloat16* tA = &sA[cur][0];
        const __hip_bfloat16* tB = &sB[cur][0];
#pragma unroll
        for (int kk = 0; kk < 2; ++kk) {
            const int ko = kk * 32 + lk * 8;
            short8 af[4], bfv[4];
#pragma unroll
            for (int f = 0; f < 4; ++f) {
                af[f]  = *reinterpret_cast<const short8*>(tA + (wr + f * 16 + lr) * 64 + ko);
                bfv[f] = *reinterpret_cast<const short8*>(tB + (wc + f * 16 + lr) * 64 + ko);
            }
#pragma unroll
            for (int i = 0; i < 4; ++i)
#pragma unroll
                for (int j = 0; j < 4; ++j)
                    acc[i][j] = __builtin_amdgcn_mfma_f32_16x16x32_bf16(af[i], bfv[j], acc[i][j], 0, 0, 0);
        }
        asm volatile("s_waitcnt lgkmcnt(0)" ::: "memory");
        __builtin_amdgcn_s_barrier();
    }
#undef STAGE

    // epilogue: C/D layout col = lane&15, row = (lane>>4)*4 + reg
#pragma unroll
    for (int i = 0; i < 4; ++i) {
#pragma unroll
        for (int j = 0; j < 4; ++j) {
            float* cp = C + (size_t)(m0 + wr + i * 16 + lk * 4) * OUTF + (n0 + wc + j * 16 + lr);
#pragma unroll
            for (int r = 0; r < 4; ++r)
                cp[(size_t)r * OUTF] = acc[i][j][r];
        }
    }
}

// ---------------------------------------------------------------------------
extern "C" void kernel_launch(void* const* d_in, const int* in_sizes, int n_in,
                              void* d_out, int out_size, void* d_ws, size_t ws_size,
                              hipStream_t stream) {
    const float* x = (const float*)d_in[0];       // (4096, 1024) fp32
    const float* w = (const float*)d_in[1];       // (1024, 1024, 8) fp32
    float* out = (float*)d_out;                   // (4096, 1024) fp32

    __hip_bfloat16* Abf = (__hip_bfloat16*)d_ws;                                   // 64 MiB
    __hip_bfloat16* Wbf = (__hip_bfloat16*)((char*)d_ws + (size_t)BATCH * KDIM * 2); // +16 MiB

    kan_bases<<<(BATCH * INF) / 256, 256, 0, stream>>>(x, (short8*)Abf);
    kan_wconv<<<(OUTF * KDIM / 8) / 256, 256, 0, stream>>>((const f32x4*)w, (short8*)Wbf);
    kan_gemm<<<256, 256, 0, stream>>>(Abf, Wbf, out);
}

// Round 2
// 144.076 us; speedup vs baseline: 1.7977x; 1.7977x over previous
//
#include <hip/hip_runtime.h>
#include <hip/hip_bf16.h>
#include <stdint.h>
#include <stddef.h>

#define BATCH 4096
#define INF   1024
#define OUTF  1024
#define NG    8
#define KDIM  (INF * NG)      // 8192
#define BK    64
#define KS    4               // split-K factor
#define KSL   (KDIM / KS)     // 2048 per slice
#define NTS   (KSL / BK)      // 32 K-iterations per block

typedef __attribute__((ext_vector_type(8))) short  short8;
typedef __attribute__((ext_vector_type(4))) float  f32x4;

// grid knots, exactly as reference: arange(-3..8)*0.4f - 1.0f, fp32
__device__ constexpr float knot(int j) { return (float)(j - 3) * 0.4f - 1.0f; }

// ---------------------------------------------------------------------------
// Kernel 1: B-spline bases. One thread per (b,i); writes 8 bf16 (16 B).
// Divides replaced by compile-time reciprocal multiplies (constants fold).
// ---------------------------------------------------------------------------
__global__ __launch_bounds__(256) void kan_bases(const float* __restrict__ x,
                                                 short8* __restrict__ A) {
    size_t idx = (size_t)blockIdx.x * 256 + threadIdx.x;
    float xv = x[idx];

    float b[11];
#pragma unroll
    for (int j = 0; j < 11; ++j)
        b[j] = (xv >= knot(j) && xv < knot(j + 1)) ? 1.0f : 0.0f;

#pragma unroll
    for (int k = 1; k <= 3; ++k) {
#pragma unroll
        for (int j = 0; j + k < 11; ++j) {
            float left  = (xv - knot(j))         * (1.0f / (knot(j + k)     - knot(j)));
            float right = (knot(j + k + 1) - xv) * (1.0f / (knot(j + k + 1) - knot(j + 1)));
            b[j] = left * b[j] + right * b[j + 1];
        }
    }

    union { short8 v; unsigned short u[8]; } pk;
#pragma unroll
    for (int g = 0; g < 8; ++g) {
        __hip_bfloat16 h = __float2bfloat16(b[g]);
        pk.u[g] = *reinterpret_cast<unsigned short*>(&h);
    }
    A[idx] = pk.v;
}

// ---------------------------------------------------------------------------
// Kernel 2: weight fp32 -> bf16 (layout already B^T row-major over k=i*8+g).
// ---------------------------------------------------------------------------
__global__ __launch_bounds__(256) void kan_wconv(const f32x4* __restrict__ w,
                                                 short8* __restrict__ Wb) {
    size_t idx = (size_t)blockIdx.x * 256 + threadIdx.x;
    f32x4 a = w[idx * 2];
    f32x4 c = w[idx * 2 + 1];
    float t[8] = {a[0], a[1], a[2], a[3], c[0], c[1], c[2], c[3]};
    union { short8 v; unsigned short u[8]; } pk;
#pragma unroll
    for (int g = 0; g < 8; ++g) {
        __hip_bfloat16 h = __float2bfloat16(t[g]);
        pk.u[g] = *reinterpret_cast<unsigned short*>(&h);
    }
    Wb[idx] = pk.v;
}

// ---------------------------------------------------------------------------
// Kernel 3: bf16 GEMM with split-K=4.
// C[4096,1024] += A[4096,8192] * Bt[1024,8192]^T   (atomic, C pre-zeroed)
// 128x128 tile, BK=64, 256 threads (4 waves), single-buffer LDS (32 KiB,
// m97 structure -> 4 blocks/CU), XOR-swizzled LDS (pre-swizzled global src
// + swizzled ds_read; rule #21 both-sides).
// ---------------------------------------------------------------------------
__device__ __forceinline__ void gload16(const void* g, void* l) {
    __builtin_amdgcn_global_load_lds((const __attribute__((address_space(1))) void*)g,
                                     (__attribute__((address_space(3))) void*)l,
                                     16, 0, 0);
}

__global__ __launch_bounds__(256) void kan_gemm(const __hip_bfloat16* __restrict__ A,
                                                const __hip_bfloat16* __restrict__ Bt,
                                                float* __restrict__ C) {
    __shared__ __hip_bfloat16 sA[128 * 64];
    __shared__ __hip_bfloat16 sB[128 * 64];

    const int tid = threadIdx.x;
    const int b   = blockIdx.x;          // b = bm*32 + bn*4 + ks
    const int ks  = b & 3;
    const int bn  = (b >> 2) & 7;
    const int bm  = b >> 5;
    const int m0  = bm << 7;
    const int n0  = bn << 7;
    const int k0  = ks * KSL;

    // staging: thread t -> LDS bytes [t*16, t*16+16) (linear, wave-uniform+lane*16)
    // = row (t>>3), 16-B slot (t&7). Source column pre-swizzled so that
    // LDS[row][e] = G[row][e ^ ((row&7)<<3)].
    const int srow = tid >> 3;                               // 0..31 (per r-step +32)
    const int scol = (((tid & 7) ^ (srow & 7)) << 3);        // swizzled src col (elems)
    const __hip_bfloat16* gA = A  + (size_t)(m0 + srow) * KDIM + k0 + scol;
    const __hip_bfloat16* gB = Bt + (size_t)(n0 + srow) * KDIM + k0 + scol;
    const int soff = tid * 8;                                // LDS elem offset

    // compute: wave w -> 64x64 quadrant
    const int w    = tid >> 6;
    const int lane = tid & 63;
    const int wr   = (w >> 1) << 6;
    const int wc   = (w & 1) << 6;
    const int lr   = lane & 15;
    const int lk   = lane >> 4;                              // 0..3
    const int sw   = (lr & 7) << 3;                          // read-side XOR (elems)

    f32x4 acc[4][4];
#pragma unroll
    for (int i = 0; i < 4; ++i)
#pragma unroll
        for (int j = 0; j < 4; ++j)
            acc[i][j] = (f32x4){0.0f, 0.0f, 0.0f, 0.0f};

    for (int kt = 0; kt < NTS; ++kt) {
        const __hip_bfloat16* ga = gA + (size_t)kt * BK;
        const __hip_bfloat16* gb = gB + (size_t)kt * BK;
#pragma unroll
        for (int r = 0; r < 4; ++r) {
            gload16(ga + (size_t)(r * 32) * KDIM, &sA[r * 2048 + soff]);
            gload16(gb + (size_t)(r * 32) * KDIM, &sB[r * 2048 + soff]);
        }
        __syncthreads();   // compiler inserts vmcnt(0) drain; TLP (4 blk/CU) hides it

#pragma unroll
        for (int kk = 0; kk < 2; ++kk) {
            const int ko = (kk * 32 + lk * 8) ^ sw;          // swizzled read col
            short8 af[4], bfv[4];
#pragma unroll
            for (int f = 0; f < 4; ++f) {
                af[f]  = *reinterpret_cast<const short8*>(sA + (wr + f * 16 + lr) * 64 + ko);
                bfv[f] = *reinterpret_cast<const short8*>(sB + (wc + f * 16 + lr) * 64 + ko);
            }
#pragma unroll
            for (int i = 0; i < 4; ++i)
#pragma unroll
                for (int j = 0; j < 4; ++j)
                    acc[i][j] = __builtin_amdgcn_mfma_f32_16x16x32_bf16(af[i], bfv[j], acc[i][j], 0, 0, 0);
        }
        __syncthreads();   // all reads done before next stage overwrites
    }

    // epilogue: C/D layout col = lane&15, row = (lane>>4)*4 + reg; atomic (split-K)
#pragma unroll
    for (int i = 0; i < 4; ++i) {
#pragma unroll
        for (int j = 0; j < 4; ++j) {
            float* cp = C + (size_t)(m0 + wr + i * 16 + lk * 4) * OUTF + (n0 + wc + j * 16 + lr);
#pragma unroll
            for (int r = 0; r < 4; ++r)
                atomicAdd(cp + (size_t)r * OUTF, acc[i][j][r]);
        }
    }
}

// ---------------------------------------------------------------------------
extern "C" void kernel_launch(void* const* d_in, const int* in_sizes, int n_in,
                              void* d_out, int out_size, void* d_ws, size_t ws_size,
                              hipStream_t stream) {
    const float* x = (const float*)d_in[0];       // (4096, 1024) fp32
    const float* w = (const float*)d_in[1];       // (1024, 1024, 8) fp32
    float* out = (float*)d_out;                   // (4096, 1024) fp32

    __hip_bfloat16* Abf = (__hip_bfloat16*)d_ws;                                     // 64 MiB
    __hip_bfloat16* Wbf = (__hip_bfloat16*)((char*)d_ws + (size_t)BATCH * KDIM * 2); // +16 MiB

    kan_bases<<<(BATCH * INF) / 256, 256, 0, stream>>>(x, (short8*)Abf);
    kan_wconv<<<(OUTF * KDIM / 8) / 256, 256, 0, stream>>>((const f32x4*)w, (short8*)Wbf);
    hipMemsetAsync(out, 0, (size_t)BATCH * OUTF * sizeof(float), stream);
    kan_gemm<<<(BATCH / 128) * (OUTF / 128) * KS, 256, 0, stream>>>(Abf, Wbf, out);
}